// Round 7
// baseline (484.022 us; speedup 1.0000x reference)
//
#include <hip/hip_runtime.h>

// Lukasiewicz t-norm feature expansion — R9 INSTRUMENTATION PROBE.
//   out[:, 0:16]    = x
//   out[:, 16:136]  = max(x[a]+x[b] - 1, 0)        (a,b)   lex combos of 16
//   out[:, 136:696] = max(x[a]+x[b]+x[c] - 2, 0)   (a,b,c) lex combos of 16
//
// Seven rounds of structural changes (op count, NT/plain stores, alignment,
// barriers, occupancy) all land at dur_us ~365-373, and the kernel has NEVER
// appeared in the top-5 dispatch table (always < the ~240us harness fills),
// so its own FETCH/WRITE/hbm_gbps have never been observed. Two models fit:
//   A: dur = fill(240) + kernel(~124us @ 2.9 TB/s)  -> memory-system cap
//      (RFO read-for-ownership would be 365wr+365rd = 116us, matching).
//   B: dur = fill(240) + hidden harness step(~120us) + kernel(~10us) -> we
//      have been at the floor since R2.
// R9 repeats the idempotent store pass REPS=3x (identical values, identical
// addresses -> final state unchanged, absmax 0):
//   Model A -> dur ~600+, kernel enters top-5 WITH counters; FETCH_SIZE
//              answers the RFO question directly.
//   Model B -> dur ~385, kernel stays invisible -> declare roofline.
// Structure otherwise identical to R8 (zero-barrier, wave-private slab).

#define NCOLS 696
#define NC4   174          // quads per row
#define RPT   16           // rows per wave-tile
#define RSTR  20           // slab row stride (floats)
#define REPS  3            // idempotent store-pass repetitions (probe)

typedef float v4f __attribute__((ext_vector_type(4)));

struct ColTab { unsigned int v[NCOLS]; };

// Packed per-column descriptor: a[4:0] | b[9:5] | c[14:10] | bias[16:15]
// index 16 -> zero slot. Order matches itertools.combinations (lex).
constexpr ColTab make_tab() {
    ColTab t{};
    int k = 0;
    for (int a = 0; a < 16; ++a)
        t.v[k++] = (unsigned)a | (16u << 5) | (16u << 10);
    for (int a = 0; a < 16; ++a)
        for (int b = a + 1; b < 16; ++b)
            t.v[k++] = (unsigned)a | ((unsigned)b << 5) | (16u << 10) | (1u << 15);
    for (int a = 0; a < 16; ++a)
        for (int b = a + 1; b < 16; ++b)
            for (int c = b + 1; c < 16; ++c)
                t.v[k++] = (unsigned)a | ((unsigned)b << 5) | ((unsigned)c << 10) | (2u << 15);
    return t;
}

__constant__ ColTab g_tab = make_tab();

__device__ __forceinline__ float tnorm(const float* __restrict__ xr, unsigned v) {
    return fmaxf(xr[v & 31u] + xr[(v >> 5) & 31u] + xr[(v >> 10) & 31u]
                 - (float)((v >> 15) & 3u), 0.0f);
}

__global__ __launch_bounds__(256) void luk_kernel_r9(const float* __restrict__ x,
                                                     float* __restrict__ out,
                                                     int nrows, int ntiles) {
    __shared__ float slabs[4][RPT * RSTR];
    const int t = threadIdx.x;
    const int w = t >> 6, lane = t & 63;
    const int tile = blockIdx.x * 4 + w;      // one tile per wave
    if (tile >= ntiles) return;               // whole-wave exit; no barriers

    float* __restrict__ slab = slabs[w];
    const int row0 = tile * RPT;
    const int rlim = min(RPT, nrows - row0);

    {   // stage: 64 lanes x dwordx4 = 16 rows x 16 floats, coalesced
        const int r  = lane >> 2;
        const int c0 = (lane & 3) * 4;
        v4f v = {0.0f, 0.0f, 0.0f, 0.0f};
        if (r < rlim)
            v = *reinterpret_cast<const v4f*>(x + (size_t)(row0 + r) * 16 + c0);
        *reinterpret_cast<v4f*>(&slab[r * RSTR + c0]) = v;
        if (lane < RPT) slab[lane * RSTR + 16] = 0.0f;   // zero slot
    }

    const uint4* __restrict__ tab4 = reinterpret_cast<const uint4*>(g_tab.v);
    v4f* __restrict__ o4 = reinterpret_cast<v4f*>(out) + (size_t)tile * (RPT * NC4);
    const int nq = rlim * NC4;

    // Probe: REPS identical passes over the same addresses with the same
    // values. Pass 1 == R8's hot loop; passes 2-3 add pure, idempotent
    // store traffic so the kernel becomes long enough to surface in the
    // rocprof top-5 with its own FETCH/WRITE counters.
    for (int rep = 0; rep < REPS; ++rep) {
        #pragma unroll 4
        for (int j = 0; j < (RPT * NC4 + 63) / 64; ++j) {
            const int q = j * 64 + lane;
            if (q < nq) {
                const unsigned r  = (unsigned)q / (unsigned)NC4;
                const int      c4 = q - (int)r * NC4;
                const uint4 tv = tab4[c4];
                const float* __restrict__ xr = &slab[r * RSTR];
                v4f o;
                o.x = tnorm(xr, tv.x);
                o.y = tnorm(xr, tv.y);
                o.z = tnorm(xr, tv.z);
                o.w = tnorm(xr, tv.w);
                o4[q] = o;
            }
        }
    }
}

extern "C" void kernel_launch(void* const* d_in, const int* in_sizes, int n_in,
                              void* d_out, int out_size, void* d_ws, size_t ws_size,
                              hipStream_t stream) {
    const float* x = (const float*)d_in[0];
    float* out = (float*)d_out;
    const int nrows  = in_sizes[0] / 16;          // 131072
    const int ntiles = (nrows + RPT - 1) / RPT;   // 8192
    const int blocks = (ntiles + 3) / 4;          // 2048
    luk_kernel_r9<<<blocks, 256, 0, stream>>>(x, out, nrows, ntiles);
}

// Round 8
// 365.477 us; speedup vs baseline: 1.3244x; 1.3244x over previous
//
#include <hip/hip_runtime.h>

// Lukasiewicz t-norm feature expansion — FINAL (R8 restored after R9 probe).
//   out[:, 0:16]    = x
//   out[:, 16:136]  = max(x[a]+x[b] - 1, 0)        (a,b)   lex combos of 16
//   out[:, 136:696] = max(x[a]+x[b]+x[c] - 2, 0)   (a,b,c) lex combos of 16
//
// Roofline evidence (R9 probe, REPS=3 idempotent store sweeps): marginal
// cost per full 365 MB output sweep = (484.0-364.8)/2 = 59.6 us = 6.13 TB/s
// = the achievable HBM write roofline (harness fill: 6.0-6.4 TB/s on the
// same buffer). So this kernel's store pass runs AT roofline; dur_us =
// ~305 us of harness (1.46 GB poison fill ~245 us + ~60 us fixed overhead)
// + ~60 us kernel. Clean variants spanning NT/plain stores, 3->8 LDS
// reads/quad, 55->12 VALU/quad, 0-2 barriers, 12-32 waves/CU all measured
// 364.8-372.9 — invariance consistent only with the kernel being pinned at
// the mandatory-write roofline (356,352 KB fp32 output).
//
// Design: one wave = one 16-row tile; LDS slab wave-private -> zero
// __syncthreads, stores never awaited (no vmcnt(0) drain anywhere).
// Stores are linear: each wave-store = 1024B contiguous, 128B-aligned.
// FP order matches jnp.sum exactly -> absmax 0.

#define NCOLS 696
#define NC4   174          // quads per row
#define RPT   16           // rows per wave-tile
#define RSTR  20           // slab row stride (floats): 16 x | zero@16 | pad

typedef float v4f __attribute__((ext_vector_type(4)));

struct ColTab { unsigned int v[NCOLS]; };

// Packed per-column descriptor: a[4:0] | b[9:5] | c[14:10] | bias[16:15]
// index 16 -> zero slot. Order matches itertools.combinations (lex).
constexpr ColTab make_tab() {
    ColTab t{};
    int k = 0;
    for (int a = 0; a < 16; ++a)
        t.v[k++] = (unsigned)a | (16u << 5) | (16u << 10);
    for (int a = 0; a < 16; ++a)
        for (int b = a + 1; b < 16; ++b)
            t.v[k++] = (unsigned)a | ((unsigned)b << 5) | (16u << 10) | (1u << 15);
    for (int a = 0; a < 16; ++a)
        for (int b = a + 1; b < 16; ++b)
            for (int c = b + 1; c < 16; ++c)
                t.v[k++] = (unsigned)a | ((unsigned)b << 5) | ((unsigned)c << 10) | (2u << 15);
    return t;
}

__constant__ ColTab g_tab = make_tab();

__device__ __forceinline__ float tnorm(const float* __restrict__ xr, unsigned v) {
    return fmaxf(xr[v & 31u] + xr[(v >> 5) & 31u] + xr[(v >> 10) & 31u]
                 - (float)((v >> 15) & 3u), 0.0f);
}

__global__ __launch_bounds__(256) void luk_kernel(const float* __restrict__ x,
                                                  float* __restrict__ out,
                                                  int nrows, int ntiles) {
    // 4 independent per-wave slabs; no __syncthreads in this kernel.
    __shared__ float slabs[4][RPT * RSTR];
    const int t = threadIdx.x;
    const int w = t >> 6, lane = t & 63;
    const int tile = blockIdx.x * 4 + w;      // one tile per wave, exactly
    if (tile >= ntiles) return;               // whole-wave exit; no barriers exist

    float* __restrict__ slab = slabs[w];
    const int row0 = tile * RPT;
    const int rlim = min(RPT, nrows - row0);

    {   // stage: 64 lanes x dwordx4 = this wave's 16 rows x 16 floats (1 KB,
        // fully coalesced). Slab row stride 80B keeps writes b128-aligned.
        const int r  = lane >> 2;
        const int c0 = (lane & 3) * 4;
        v4f v = {0.0f, 0.0f, 0.0f, 0.0f};
        if (r < rlim)
            v = *reinterpret_cast<const v4f*>(x + (size_t)(row0 + r) * 16 + c0);
        *reinterpret_cast<v4f*>(&slab[r * RSTR + c0]) = v;
        if (lane < RPT) slab[lane * RSTR + 16] = 0.0f;   // zero slot
    }
    // wave-private RAW through LDS: compiler inserts s_waitcnt lgkmcnt; no
    // cross-wave visibility needed, so no s_barrier and NO vmcnt(0) drain.

    const uint4* __restrict__ tab4 = reinterpret_cast<const uint4*>(g_tab.v);
    v4f* __restrict__ o4 = reinterpret_cast<v4f*>(out) + (size_t)tile * (RPT * NC4);
    const int nq = rlim * NC4;                // 2784 for full tiles

    // 44 iterations; each wave-store = 64 lanes x 16B = 1024B contiguous,
    // 128B-line-aligned (tile base = tile*44544B). Stores are never waited
    // on: they drain while the LDS pipe works on subsequent iterations.
    #pragma unroll 4
    for (int j = 0; j < (RPT * NC4 + 63) / 64; ++j) {
        const int q = j * 64 + lane;
        if (q < nq) {
            const unsigned r  = (unsigned)q / (unsigned)NC4;
            const int      c4 = q - (int)r * NC4;
            const uint4 tv = tab4[c4];
            const float* __restrict__ xr = &slab[r * RSTR];
            v4f o;
            o.x = tnorm(xr, tv.x);
            o.y = tnorm(xr, tv.y);
            o.z = tnorm(xr, tv.z);
            o.w = tnorm(xr, tv.w);
            o4[q] = o;
        }
    }
}

extern "C" void kernel_launch(void* const* d_in, const int* in_sizes, int n_in,
                              void* d_out, int out_size, void* d_ws, size_t ws_size,
                              hipStream_t stream) {
    const float* x = (const float*)d_in[0];
    float* out = (float*)d_out;
    const int nrows  = in_sizes[0] / 16;          // 131072
    const int ntiles = (nrows + RPT - 1) / RPT;   // 8192
    const int blocks = (ntiles + 3) / 4;          // 2048: 8 blocks/CU, 32 waves/CU
    luk_kernel<<<blocks, 256, 0, stream>>>(x, out, nrows, ntiles);
}